// Round 1
// baseline (1013.063 us; speedup 1.0000x reference)
//
#include <hip/hip_runtime.h>

#define BB 2
#define SS 2048
#define DD 1024
#define HH 16
#define WW 64
#define MM (BB*SS)  // 4096

typedef float f32x4 __attribute__((ext_vector_type(4)));
typedef short s16x8 __attribute__((ext_vector_type(8)));

__device__ __forceinline__ unsigned short f2bf(float f) {
  return __builtin_bit_cast(unsigned short, (__bf16)f);
}
__device__ __forceinline__ float bf2f(unsigned short u) {
  return (float)__builtin_bit_cast(__bf16, u);
}
__device__ __forceinline__ float rlane(float v, int l) {
  return __builtin_bit_cast(float, __builtin_amdgcn_readlane(__builtin_bit_cast(int, v), l));
}

// ---------------- pre-pass: x fp32 -> bf16 ----------------
__global__ __launch_bounds__(256) void k_convert_x(const float* __restrict__ x,
                                                   unsigned short* __restrict__ xb) {
  int i = (blockIdx.x * 256 + threadIdx.x) * 4;
  float4 v = *(const float4*)(x + i);
  ushort4 o = make_ushort4(f2bf(v.x), f2bf(v.y), f2bf(v.z), f2bf(v.w));
  *(ushort4*)(xb + i) = o;
}

// ---------------- pre-pass: W (KxN fp32) -> Wt (NxK bf16) ----------------
__global__ __launch_bounds__(256) void k_transpose_w(const float* __restrict__ Wm,
                                                     unsigned short* __restrict__ Wt) {
  __shared__ float tile[32][33];
  int bn = blockIdx.x * 32;  // n (cols of W)
  int bk = blockIdx.y * 32;  // k (rows of W)
  int tx = threadIdx.x;      // 0..31
  int ty = threadIdx.y;      // 0..7
#pragma unroll
  for (int r = 0; r < 4; ++r)
    tile[ty + r * 8][tx] = Wm[(bk + ty + r * 8) * DD + bn + tx];
  __syncthreads();
#pragma unroll
  for (int r = 0; r < 4; ++r)
    Wt[(bn + ty + r * 8) * DD + bk + tx] = f2bf(tile[tx][ty + r * 8]);
}

// ---------------- bf16 MFMA GEMM: C = A(M,K) * Bt(N,K)^T + bias ----------------
// modes: 0 = write bf16 head-layout (B,H,S,W), scaled (Q)
//        1 = write bf16 per-head transposed (B,H,W,S)  (K^T)
//        2 = write bf16 head-layout (V)
//        3 = write fp32 row-major MxN (final output)
__global__ __launch_bounds__(256) void k_gemm(const unsigned short* __restrict__ A,
                                              const unsigned short* __restrict__ Bt,
                                              const float* __restrict__ bias,
                                              unsigned short* __restrict__ out_bf,
                                              float* __restrict__ out_f,
                                              int mode, float oscale) {
  constexpr int LDK = 40;  // padded K-stride (16B aligned rows, 2-way bank alias = free)
  __shared__ __align__(16) unsigned short As[64 * LDK];
  __shared__ __align__(16) unsigned short Bs[64 * LDK];
  const int m0 = blockIdx.y * 64, n0 = blockIdx.x * 64;
  const int t = threadIdx.x;
  const int wv = t >> 6, lane = t & 63;
  const int quad = lane >> 4, l16 = lane & 15;
  const int sr = t >> 2, sk = (t & 3) * 8;      // staging: row, k-offset (8 bf16 = 16B)
  const int wm = (wv >> 1) * 32, wn = (wv & 1) * 32;  // 2x2 wave arrangement
  f32x4 acc[2][2] = {};

  for (int k0 = 0; k0 < DD; k0 += 32) {
    uint4 av = *(const uint4*)(A + (m0 + sr) * DD + k0 + sk);
    uint4 bv = *(const uint4*)(Bt + (n0 + sr) * DD + k0 + sk);
    __syncthreads();
    *(uint4*)(As + sr * LDK + sk) = av;
    *(uint4*)(Bs + sr * LDK + sk) = bv;
    __syncthreads();
    s16x8 af[2], bfr[2];
#pragma unroll
    for (int i = 0; i < 2; ++i) {
      af[i]  = *(const s16x8*)(As + (wm + i * 16 + l16) * LDK + quad * 8);
      bfr[i] = *(const s16x8*)(Bs + (wn + i * 16 + l16) * LDK + quad * 8);
    }
#pragma unroll
    for (int mi = 0; mi < 2; ++mi)
#pragma unroll
      for (int ni = 0; ni < 2; ++ni)
        acc[mi][ni] = __builtin_amdgcn_mfma_f32_16x16x32_bf16(af[mi], bfr[ni], acc[mi][ni], 0, 0, 0);
  }

#pragma unroll
  for (int mi = 0; mi < 2; ++mi) {
#pragma unroll
    for (int ni = 0; ni < 2; ++ni) {
      int col = n0 + wn + ni * 16 + l16;
      float bb = bias[col];
#pragma unroll
      for (int r = 0; r < 4; ++r) {
        int row = m0 + wm + mi * 16 + quad * 4 + r;  // C/D: row = quad*4 + reg
        float v = (acc[mi][ni][r] + bb) * oscale;
        if (mode == 3) {
          out_f[row * DD + col] = v;
        } else {
          int b = row >> 11, s = row & (SS - 1);
          int h = col >> 6, w = col & 63;
          long off;
          if (mode == 1) off = (long)(b * HH + h) * (SS * WW) + (long)w * SS + s;
          else           off = (long)(b * HH + h) * (SS * WW) + (long)s * WW + w;
          out_bf[off] = f2bf(v);
        }
      }
    }
  }
}

// ---------------- flash attention, fp32 vector, register-resident ----------------
// grid: (S/32, B*H); block: 256 (4 waves x 8 query rows); keys in 64-wide tiles
__global__ __launch_bounds__(256) void k_attn(const unsigned short* __restrict__ Q,
                                              const unsigned short* __restrict__ Kt,
                                              const unsigned short* __restrict__ V,
                                              unsigned short* __restrict__ hm) {
  const int qb = blockIdx.x * 32;
  const int bh = blockIdx.y;
  const int t = threadIdx.x;
  const int wv = t >> 6, lane = t & 63;
  const unsigned short* Qp = Q + (size_t)bh * SS * WW;
  const unsigned short* Kp = Kt + (size_t)bh * WW * SS;
  const unsigned short* Vp = V + (size_t)bh * SS * WW;
  const int r0 = qb + wv * 8;

  float q[8], O[8], m[8], l[8], p[8];
#pragma unroll
  for (int i = 0; i < 8; ++i) {
    q[i] = bf2f(Qp[(r0 + i) * WW + lane]);  // Q already scaled by 1/8 in projection
    O[i] = 0.f;
    m[i] = -__builtin_inff();
    l[i] = 0.f;
  }

  const int ktiles = qb / 64 + 1;  // causal: only tiles with keys <= max query
  for (int kt = 0; kt < ktiles; ++kt) {
    const int kb = kt * 64;
    float KV[64];
    // K tile: lane holds key (kb+lane)'s 64-dim vector (coalesced via K^T layout)
#pragma unroll
    for (int w = 0; w < 64; ++w) KV[w] = bf2f(Kp[w * SS + kb + lane]);

    float sc[8];
#pragma unroll
    for (int i = 0; i < 8; ++i) sc[i] = 0.f;
#pragma unroll
    for (int w = 0; w < 64; ++w) {
#pragma unroll
      for (int i = 0; i < 8; ++i) sc[i] = fmaf(rlane(q[i], w), KV[w], sc[i]);
    }

    if (kt == ktiles - 1) {
#pragma unroll
      for (int i = 0; i < 8; ++i)
        if (kb + lane > r0 + i) sc[i] = -__builtin_inff();
    }

#pragma unroll
    for (int i = 0; i < 8; ++i) {
      float smax = sc[i];
#pragma unroll
      for (int xm = 32; xm >= 1; xm >>= 1) smax = fmaxf(smax, __shfl_xor(smax, xm));
      float mnew = fmaxf(m[i], smax);
      float alpha = __expf(m[i] - mnew);   // first tile: exp(-inf - finite) = 0
      float pv = __expf(sc[i] - mnew);     // masked lanes: exp(-inf) = 0
      float ps = pv;
#pragma unroll
      for (int xm = 32; xm >= 1; xm >>= 1) ps += __shfl_xor(ps, xm);
      l[i] = l[i] * alpha + ps;
      m[i] = mnew;
      O[i] *= alpha;
      p[i] = pv;
    }

    // V tile into same registers: lane holds dim `lane` of key (kb+j) per iter
#pragma unroll
    for (int j = 0; j < 64; ++j) KV[j] = bf2f(Vp[(kb + j) * WW + lane]);
#pragma unroll
    for (int j = 0; j < 64; ++j) {
#pragma unroll
      for (int i = 0; i < 8; ++i) O[i] = fmaf(rlane(p[i], j), KV[j], O[i]);
    }
  }

  const int b = bh >> 4, h = bh & 15;
#pragma unroll
  for (int i = 0; i < 8; ++i) {
    float v = O[i] / l[i];
    hm[(size_t)(b * SS + r0 + i) * DD + h * WW + lane] = f2bf(v);
  }
}

extern "C" void kernel_launch(void* const* d_in, const int* in_sizes, int n_in,
                              void* d_out, int out_size, void* d_ws, size_t ws_size,
                              hipStream_t stream) {
  const float* x  = (const float*)d_in[0];
  // d_in[1] = seg : unused by the reference
  const float* Wq = (const float*)d_in[2];
  const float* bq = (const float*)d_in[3];
  const float* Wk = (const float*)d_in[4];
  const float* bk = (const float*)d_in[5];
  const float* Wv = (const float*)d_in[6];
  const float* bv = (const float*)d_in[7];
  const float* Wo = (const float*)d_in[8];
  const float* bo = (const float*)d_in[9];
  float* out = (float*)d_out;

  char* ws = (char*)d_ws;
  unsigned short* xb  = (unsigned short*)(ws);                      // 8 MB  (4096x1024 bf16)
  unsigned short* Wtq = (unsigned short*)(ws + (size_t)( 8 << 20)); // 2 MB each
  unsigned short* Wtk = (unsigned short*)(ws + (size_t)(10 << 20));
  unsigned short* Wtv = (unsigned short*)(ws + (size_t)(12 << 20));
  unsigned short* Wto = (unsigned short*)(ws + (size_t)(14 << 20));
  unsigned short* Qb  = (unsigned short*)(ws + (size_t)(16 << 20)); // 8 MB (B,H,S,W)
  unsigned short* Ktb = (unsigned short*)(ws + (size_t)(24 << 20)); // 8 MB (B,H,W,S)
  unsigned short* Vb  = (unsigned short*)(ws + (size_t)(32 << 20)); // 8 MB (B,H,S,W)
  unsigned short* hm  = (unsigned short*)(ws + (size_t)(40 << 20)); // 8 MB (B,S,D) -> 48 MB total

  k_convert_x<<<dim3(MM * DD / 1024), 256, 0, stream>>>(x, xb);

  dim3 tg(32, 32), tb(32, 8);
  k_transpose_w<<<tg, tb, 0, stream>>>(Wq, Wtq);
  k_transpose_w<<<tg, tb, 0, stream>>>(Wk, Wtk);
  k_transpose_w<<<tg, tb, 0, stream>>>(Wv, Wtv);
  k_transpose_w<<<tg, tb, 0, stream>>>(Wo, Wto);

  dim3 gg(DD / 64, MM / 64);  // (16, 64)
  k_gemm<<<gg, 256, 0, stream>>>(xb, Wtq, bq, Qb, nullptr, 0, 0.125f);  // Q, pre-scaled 1/sqrt(64)
  k_gemm<<<gg, 256, 0, stream>>>(xb, Wtk, bk, Ktb, nullptr, 1, 1.0f);   // K^T
  k_gemm<<<gg, 256, 0, stream>>>(xb, Wtv, bv, Vb, nullptr, 2, 1.0f);    // V

  dim3 ag(SS / 32, BB * HH);  // (64, 32)
  k_attn<<<ag, 256, 0, stream>>>(Qb, Ktb, Vb, hm);

  k_gemm<<<gg, 256, 0, stream>>>(hm, Wto, bo, nullptr, out, 3, 1.0f);   // final projection, fp32
}

// Round 2
// 315.523 us; speedup vs baseline: 3.2107x; 3.2107x over previous
//
#include <hip/hip_runtime.h>

#define BB 2
#define SS 2048
#define DD 1024
#define HH 16
#define WW 64
#define MM (BB*SS)  // 4096

typedef float f32x4 __attribute__((ext_vector_type(4)));
typedef short s16x8 __attribute__((ext_vector_type(8)));

__device__ __forceinline__ unsigned short f2bf(float f) {
  return __builtin_bit_cast(unsigned short, (__bf16)f);
}
__device__ __forceinline__ float bf2f(unsigned short u) {
  return (float)__builtin_bit_cast(__bf16, u);
}

// ---------------- pre-pass: x fp32 -> bf16 ----------------
__global__ __launch_bounds__(256) void k_convert_x(const float* __restrict__ x,
                                                   unsigned short* __restrict__ xb) {
  int i = (blockIdx.x * 256 + threadIdx.x) * 4;
  float4 v = *(const float4*)(x + i);
  ushort4 o = make_ushort4(f2bf(v.x), f2bf(v.y), f2bf(v.z), f2bf(v.w));
  *(ushort4*)(xb + i) = o;
}

// ---------------- pre-pass: W (KxN fp32) -> Wt (NxK bf16) ----------------
__global__ __launch_bounds__(256) void k_transpose_w(const float* __restrict__ Wm,
                                                     unsigned short* __restrict__ Wt) {
  __shared__ float tile[32][33];
  int bn = blockIdx.x * 32;  // n (cols of W)
  int bk = blockIdx.y * 32;  // k (rows of W)
  int tx = threadIdx.x;      // 0..31
  int ty = threadIdx.y;      // 0..7
#pragma unroll
  for (int r = 0; r < 4; ++r)
    tile[ty + r * 8][tx] = Wm[(bk + ty + r * 8) * DD + bn + tx];
  __syncthreads();
#pragma unroll
  for (int r = 0; r < 4; ++r)
    Wt[(bn + ty + r * 8) * DD + bk + tx] = f2bf(tile[tx][ty + r * 8]);
}

// ---------------- bf16 MFMA GEMM: C = A(M,K) * Bt(N,K)^T + bias ----------------
// modes: 0 = write bf16 head-layout (B,H,S,W), scaled (Q)
//        1 = write bf16 per-head transposed (B,H,W,S)  (V^T)
//        2 = write bf16 head-layout (K)
//        3 = write fp32 row-major MxN (final output)
__global__ __launch_bounds__(256) void k_gemm(const unsigned short* __restrict__ A,
                                              const unsigned short* __restrict__ Bt,
                                              const float* __restrict__ bias,
                                              unsigned short* __restrict__ out_bf,
                                              float* __restrict__ out_f,
                                              int mode, float oscale) {
  constexpr int LDK = 40;  // padded K-stride (16B aligned rows, 2-way bank alias = free)
  __shared__ __align__(16) unsigned short As[64 * LDK];
  __shared__ __align__(16) unsigned short Bs[64 * LDK];
  const int m0 = blockIdx.y * 64, n0 = blockIdx.x * 64;
  const int t = threadIdx.x;
  const int wv = t >> 6, lane = t & 63;
  const int quad = lane >> 4, l16 = lane & 15;
  const int sr = t >> 2, sk = (t & 3) * 8;      // staging: row, k-offset (8 bf16 = 16B)
  const int wm = (wv >> 1) * 32, wn = (wv & 1) * 32;  // 2x2 wave arrangement
  f32x4 acc[2][2] = {};

  for (int k0 = 0; k0 < DD; k0 += 32) {
    uint4 av = *(const uint4*)(A + (m0 + sr) * DD + k0 + sk);
    uint4 bv = *(const uint4*)(Bt + (n0 + sr) * DD + k0 + sk);
    __syncthreads();
    *(uint4*)(As + sr * LDK + sk) = av;
    *(uint4*)(Bs + sr * LDK + sk) = bv;
    __syncthreads();
    s16x8 af[2], bfr[2];
#pragma unroll
    for (int i = 0; i < 2; ++i) {
      af[i]  = *(const s16x8*)(As + (wm + i * 16 + l16) * LDK + quad * 8);
      bfr[i] = *(const s16x8*)(Bs + (wn + i * 16 + l16) * LDK + quad * 8);
    }
#pragma unroll
    for (int mi = 0; mi < 2; ++mi)
#pragma unroll
      for (int ni = 0; ni < 2; ++ni)
        acc[mi][ni] = __builtin_amdgcn_mfma_f32_16x16x32_bf16(af[mi], bfr[ni], acc[mi][ni], 0, 0, 0);
  }

#pragma unroll
  for (int mi = 0; mi < 2; ++mi) {
#pragma unroll
    for (int ni = 0; ni < 2; ++ni) {
      int col = n0 + wn + ni * 16 + l16;
      float bb = bias[col];
#pragma unroll
      for (int r = 0; r < 4; ++r) {
        int row = m0 + wm + mi * 16 + quad * 4 + r;  // C/D: row = quad*4 + reg
        float v = (acc[mi][ni][r] + bb) * oscale;
        if (mode == 3) {
          out_f[row * DD + col] = v;
        } else {
          int b = row >> 11, s = row & (SS - 1);
          int h = col >> 6, w = col & 63;
          long off;
          if (mode == 1) off = (long)(b * HH + h) * (SS * WW) + (long)w * SS + s;
          else           off = (long)(b * HH + h) * (SS * WW) + (long)s * WW + w;
          out_bf[off] = f2bf(v);
        }
      }
    }
  }
}

// ---------------- MFMA flash attention ----------------
// One wave (64 threads) per (b,h, 32-query tile). Keys in 64-wide tiles.
// Q,K in (B,H,S,W) bf16 (Q pre-scaled by 1/8); Vt in (B,H,W,S) bf16.
// Scores computed as S^T = K*Q^T so that:
//   - softmax reduction over keys = reg-reduce + shfl_xor(16,32)
//   - P store to LDS [q][key] is contiguous per lane (ds_write_b64)
__global__ __launch_bounds__(64) void k_attn_mfma(const unsigned short* __restrict__ Q,
                                                  const unsigned short* __restrict__ K,
                                                  const unsigned short* __restrict__ Vt,
                                                  unsigned short* __restrict__ hm) {
  constexpr int LDP = 72;  // row stride (elems): 144 B -> b128 reads 16B-aligned, 2-way bank alias
  __shared__ __align__(16) unsigned short Pl[32 * LDP];
  const int qb = blockIdx.x * 32;
  const int bh = blockIdx.y;
  const int lane = threadIdx.x;
  const int quad = lane >> 4, l16 = lane & 15;
  const unsigned short* Qp = Q + (size_t)bh * SS * WW;
  const unsigned short* Kp = K + (size_t)bh * SS * WW;
  const unsigned short* Vp = Vt + (size_t)bh * WW * SS;

  // Q B-fragments (loop-invariant): B[n=q_local=l16][k=dim=quad*8+j], nt = q 16-tile, c = 32-dim chunk
  s16x8 qf[2][2];
#pragma unroll
  for (int nt = 0; nt < 2; ++nt)
#pragma unroll
    for (int c = 0; c < 2; ++c)
      qf[nt][c] = *(const s16x8*)(Qp + (qb + nt * 16 + l16) * WW + c * 32 + quad * 8);

  f32x4 O[2][4] = {};          // O[mi=q 16-tile][ni=dim 16-tile]; C/D: row=q=quad*4+r, col=dim=l16
  float m[2], l[2];
  m[0] = m[1] = -__builtin_inff();
  l[0] = l[1] = 0.f;

  const int ktiles = qb / 64 + 1;
  for (int kt = 0; kt < ktiles; ++kt) {
    const int kb = kt * 64;

    // K A-fragments: A[m=key_local][k=dim]
    s16x8 kf[4][2];
#pragma unroll
    for (int mt = 0; mt < 4; ++mt)
#pragma unroll
      for (int c = 0; c < 2; ++c)
        kf[mt][c] = *(const s16x8*)(Kp + (kb + mt * 16 + l16) * WW + c * 32 + quad * 8);

    // V^T B-fragments: B[n=dim_local][k=key]
    s16x8 vf[4][2];
#pragma unroll
    for (int ni = 0; ni < 4; ++ni)
#pragma unroll
      for (int c = 0; c < 2; ++c)
        vf[ni][c] = *(const s16x8*)(Vp + (ni * 16 + l16) * SS + kb + c * 32 + quad * 8);

    // S^T tiles: sc[mt][nt], row=key_local=quad*4+r (+16*mt), col=q_local=l16 (+16*nt)
    f32x4 sc[4][2] = {};
#pragma unroll
    for (int mt = 0; mt < 4; ++mt)
#pragma unroll
      for (int nt = 0; nt < 2; ++nt)
#pragma unroll
        for (int c = 0; c < 2; ++c)
          sc[mt][nt] = __builtin_amdgcn_mfma_f32_16x16x32_bf16(kf[mt][c], qf[nt][c], sc[mt][nt], 0, 0, 0);

    // causal mask (only the diagonal-overlapping last tile)
    if (kt == ktiles - 1) {
#pragma unroll
      for (int mt = 0; mt < 4; ++mt)
#pragma unroll
        for (int nt = 0; nt < 2; ++nt)
#pragma unroll
          for (int r = 0; r < 4; ++r)
            if (kb + mt * 16 + quad * 4 + r > qb + nt * 16 + l16)
              sc[mt][nt][r] = -__builtin_inff();
    }

    // online softmax update; stats per q = nt*16 + l16 (replicated across quads)
    float alpha[2];
#pragma unroll
    for (int nt = 0; nt < 2; ++nt) {
      float mx = sc[0][nt][0];
#pragma unroll
      for (int mt = 0; mt < 4; ++mt)
#pragma unroll
        for (int r = 0; r < 4; ++r) mx = fmaxf(mx, sc[mt][nt][r]);
      mx = fmaxf(mx, __shfl_xor(mx, 16));
      mx = fmaxf(mx, __shfl_xor(mx, 32));
      float mn = fmaxf(m[nt], mx);
      alpha[nt] = __expf(m[nt] - mn);
      float s = 0.f;
#pragma unroll
      for (int mt = 0; mt < 4; ++mt)
#pragma unroll
        for (int r = 0; r < 4; ++r) {
          float p = __expf(sc[mt][nt][r] - mn);
          sc[mt][nt][r] = p;
          s += p;
        }
      s += __shfl_xor(s, 16);
      s += __shfl_xor(s, 32);
      l[nt] = l[nt] * alpha[nt] + s;
      m[nt] = mn;
    }

    // rescale O: rows are q = mi*16 + quad*4 + r -> broadcast alpha from lane (quad*4+r)
#pragma unroll
    for (int mi = 0; mi < 2; ++mi)
#pragma unroll
      for (int r = 0; r < 4; ++r) {
        float aT = __shfl(alpha[mi], quad * 4 + r);
#pragma unroll
        for (int ni = 0; ni < 4; ++ni) O[mi][ni][r] *= aT;
      }

    // P -> LDS [q][key] (bf16), contiguous 4-key runs per lane
    __syncthreads();  // WAR: previous iteration's reads done
#pragma unroll
    for (int mt = 0; mt < 4; ++mt)
#pragma unroll
      for (int nt = 0; nt < 2; ++nt) {
        ushort4 pw = make_ushort4(f2bf(sc[mt][nt][0]), f2bf(sc[mt][nt][1]),
                                  f2bf(sc[mt][nt][2]), f2bf(sc[mt][nt][3]));
        *(ushort4*)(Pl + (nt * 16 + l16) * LDP + mt * 16 + quad * 4) = pw;
      }
    __syncthreads();

    // P A-fragments: A[m=q_local=l16][k=key=quad*8+j]
    s16x8 pf[2][2];
#pragma unroll
    for (int mi = 0; mi < 2; ++mi)
#pragma unroll
      for (int c = 0; c < 2; ++c)
        pf[mi][c] = *(const s16x8*)(Pl + (mi * 16 + l16) * LDP + c * 32 + quad * 8);

    // O += P * V^T
#pragma unroll
    for (int mi = 0; mi < 2; ++mi)
#pragma unroll
      for (int ni = 0; ni < 4; ++ni)
#pragma unroll
        for (int c = 0; c < 2; ++c)
          O[mi][ni] = __builtin_amdgcn_mfma_f32_16x16x32_bf16(pf[mi][c], vf[ni][c], O[mi][ni], 0, 0, 0);
  }

  // epilogue: divide by l (broadcast per C/D row), write head-merged (B,S,D)
  const int b = bh >> 4, h = bh & 15;
#pragma unroll
  for (int mi = 0; mi < 2; ++mi)
#pragma unroll
    for (int r = 0; r < 4; ++r) {
      float linv = 1.f / __shfl(l[mi], quad * 4 + r);
      int q = qb + mi * 16 + quad * 4 + r;
#pragma unroll
      for (int ni = 0; ni < 4; ++ni)
        hm[(size_t)(b * SS + q) * DD + h * WW + ni * 16 + l16] = f2bf(O[mi][ni][r] * linv);
    }
}

extern "C" void kernel_launch(void* const* d_in, const int* in_sizes, int n_in,
                              void* d_out, int out_size, void* d_ws, size_t ws_size,
                              hipStream_t stream) {
  const float* x  = (const float*)d_in[0];
  // d_in[1] = seg : unused by the reference
  const float* Wq = (const float*)d_in[2];
  const float* bq = (const float*)d_in[3];
  const float* Wk = (const float*)d_in[4];
  const float* bk = (const float*)d_in[5];
  const float* Wv = (const float*)d_in[6];
  const float* bv = (const float*)d_in[7];
  const float* Wo = (const float*)d_in[8];
  const float* bo = (const float*)d_in[9];
  float* out = (float*)d_out;

  char* ws = (char*)d_ws;
  unsigned short* xb  = (unsigned short*)(ws);                      // 8 MB  (4096x1024 bf16)
  unsigned short* Wtq = (unsigned short*)(ws + (size_t)( 8 << 20)); // 2 MB each
  unsigned short* Wtk = (unsigned short*)(ws + (size_t)(10 << 20));
  unsigned short* Wtv = (unsigned short*)(ws + (size_t)(12 << 20));
  unsigned short* Wto = (unsigned short*)(ws + (size_t)(14 << 20));
  unsigned short* Qb  = (unsigned short*)(ws + (size_t)(16 << 20)); // 8 MB (B,H,S,W)
  unsigned short* Kb  = (unsigned short*)(ws + (size_t)(24 << 20)); // 8 MB (B,H,S,W)
  unsigned short* Vtb = (unsigned short*)(ws + (size_t)(32 << 20)); // 8 MB (B,H,W,S)
  unsigned short* hm  = (unsigned short*)(ws + (size_t)(40 << 20)); // 8 MB (B,S,D) -> 48 MB total

  k_convert_x<<<dim3(MM * DD / 1024), 256, 0, stream>>>(x, xb);

  dim3 tg(32, 32), tb(32, 8);
  k_transpose_w<<<tg, tb, 0, stream>>>(Wq, Wtq);
  k_transpose_w<<<tg, tb, 0, stream>>>(Wk, Wtk);
  k_transpose_w<<<tg, tb, 0, stream>>>(Wv, Wtv);
  k_transpose_w<<<tg, tb, 0, stream>>>(Wo, Wto);

  dim3 gg(DD / 64, MM / 64);  // (16, 64)
  k_gemm<<<gg, 256, 0, stream>>>(xb, Wtq, bq, Qb, nullptr, 0, 0.125f);  // Q, pre-scaled 1/sqrt(64)
  k_gemm<<<gg, 256, 0, stream>>>(xb, Wtk, bk, Kb, nullptr, 2, 1.0f);    // K head-layout
  k_gemm<<<gg, 256, 0, stream>>>(xb, Wtv, bv, Vtb, nullptr, 1, 1.0f);   // V^T per head
  dim3 ag(SS / 32, BB * HH);  // (64, 32)
  k_attn_mfma<<<ag, 64, 0, stream>>>(Qb, Kb, Vtb, hm);

  k_gemm<<<gg, 256, 0, stream>>>(hm, Wto, bo, nullptr, out, 3, 1.0f);   // final projection, fp32
}